// Round 19
// baseline (323.754 us; speedup 1.0000x reference)
//
#include <hip/hip_runtime.h>

#define SQ   2048
#define HIDN 1024
#define NB   4
#define NH   16
#define HD   64

typedef __attribute__((ext_vector_type(8))) short short8;
typedef __attribute__((ext_vector_type(4))) short short4v;
typedef __attribute__((ext_vector_type(4))) float f32x4;

__device__ __forceinline__ short f2bf(float f) {
  union { float f; unsigned u; } x; x.f = f;
  unsigned r = (x.u + 0x7fffu + ((x.u >> 16) & 1u)) >> 16;
  return (short)r;
}

__device__ __forceinline__ unsigned cvtpk_bf16(float lo, float hi) {
  unsigned u;
  asm("v_cvt_pk_bf16_f32 %0, %1, %2" : "=v"(u) : "v"(lo), "v"(hi));
  return u;
}

__device__ __forceinline__ float exp2_raw(float x) {
  float r;
  asm("v_exp_f32 %0, %1" : "=v"(r) : "v"(x));   // r = 2^x, register-only
  return r;
}

#define MFMA(a, b, c) __builtin_amdgcn_mfma_f32_16x16x32_bf16((a), (b), (c), 0, 0, 0)

__device__ __forceinline__ void gload16(const void* g, void* l) {
  __builtin_amdgcn_global_load_lds(
      (const __attribute__((address_space(1))) unsigned*)g,
      (__attribute__((address_space(3))) unsigned*)l, 16, 0, 0);
}

#define LOG2E 1.44269504f

// ---------------------------------------------------------------------------
// K0: normalize mask to fp32 (auto-detect int32 / byte-bool / fp32). Verified.
// ---------------------------------------------------------------------------
__global__ __launch_bounds__(256) void k_maskprep(const unsigned* __restrict__ mraw,
                                                  float* __restrict__ m) {
  __shared__ unsigned red[256];
  const int tid = threadIdx.x;
  unsigned w_or = 0;
  for (int i = tid; i < 2048; i += 256) w_or |= mraw[i];
  red[tid] = w_or;
  __syncthreads();
  for (int s = 128; s > 0; s >>= 1) {
    if (tid < s) red[tid] |= red[tid + s];
    __syncthreads();
  }
  const unsigned allw = red[0];
  int mode;
  if ((allw & 0xFFFFFFFEu) == 0) mode = 0;
  else if ((allw & 0xFEFEFEFEu) == 0) mode = 1;
  else mode = 2;
  const unsigned char* mb = (const unsigned char*)mraw;
  const float* mf = (const float*)mraw;
  const int* mi = (const int*)mraw;
  for (int i = tid; i < NB * SQ; i += 256) {
    float v;
    if (mode == 0)      v = mi[i] ? 1.0f : 0.0f;
    else if (mode == 1) v = mb[i] ? 1.0f : 0.0f;
    else                v = (mf[i] != 0.0f) ? 1.0f : 0.0f;
    m[i] = v;
  }
}

// ---------------------------------------------------------------------------
// K0b: fp32 -> bf16 pre-convert. y=0: query -> qbf; y=1..3: Wq/Wk/Wv -> wbf.
// ---------------------------------------------------------------------------
__global__ __launch_bounds__(256) void k_cvt(
    const float* __restrict__ query, const float* __restrict__ Wq,
    const float* __restrict__ Wk, const float* __restrict__ Wv,
    short* __restrict__ qbf, short* __restrict__ wbf)
{
  const int yy = blockIdx.y;
  const float* __restrict__ src = (yy == 0) ? query : (yy == 1) ? Wq : (yy == 2) ? Wk : Wv;
  short* __restrict__ dst = (yy == 0) ? qbf : wbf + (yy - 1) * (HIDN * HIDN);
  const int n = (yy == 0) ? (NB * SQ * HIDN) : (HIDN * HIDN);
  const int i = (blockIdx.x * 256 + threadIdx.x) * 4;
  if (i >= n) return;
  const f32x4 v = *(const f32x4*)(src + i);
  short4v s;
#pragma unroll
  for (int e = 0; e < 4; ++e) s[e] = f2bf(v[e]);
  *(short4v*)(dst + i) = s;
}

// K0c: Wo -> bf16 (runs after attnv, into the then-dead qh region).
__global__ __launch_bounds__(256) void k_cvtWo(
    const float* __restrict__ Wo, short* __restrict__ wo)
{
  const int i = (blockIdx.x * 256 + threadIdx.x) * 4;
  if (i >= HIDN * HIDN) return;
  const f32x4 v = *(const f32x4*)(Wo + i);
  short4v s;
#pragma unroll
  for (int e = 0; e < 4; ++e) s[e] = f2bf(v[e]);
  *(short4v*)(wo + i) = s;
}

// ---------------------------------------------------------------------------
// K1 v6: fused QKV projection GEMM, 256x128 tile (A-panel reuse doubled),
// 4 waves stacked in M (wave = 64x128, acc 4x8), BK=64, single-buffer 48KB
// LDS, both-sides XOR swizzle, gload_lds staging. Per-output staged bytes
// and ds_read count both -25% vs the 128^2 tile. No XCD swizzle (falsified).
// ---------------------------------------------------------------------------
__global__ __launch_bounds__(256) void k_proj_qkv4(
    const short* __restrict__ qbf, const short* __restrict__ wbf,
    const float* __restrict__ bq, const float* __restrict__ bkb,
    const float* __restrict__ bv, const float* __restrict__ mfl,
    short* __restrict__ qh, short* __restrict__ kh, short* __restrict__ vh)
{
  __shared__ short a_s[256 * 64];   // 32 KB
  __shared__ short b_s[128 * 64];   // 16 KB
  const int nt = blockIdx.x, mt = blockIdx.y;   // nt 0..23, mt 0..31
  const int tid = threadIdx.x;
  const int w = tid >> 6, lane = tid & 63;
  const int lg = lane >> 4, lr = lane & 15;

  const int z = nt >> 3;   // block-uniform: 0=q, 1=k, 2=v
  const float* __restrict__ bias = (z == 0) ? bq : (z == 1) ? bkb : bv;

  // staging maps (chunk id -> row, pre-swizzled source chunk)
  int rA[8], cA[8], dA[8];
#pragma unroll
  for (int p = 0; p < 8; ++p) {
    const int id = p * 256 + tid;
    rA[p] = id >> 3;
    cA[p] = (id & 7) ^ (rA[p] & 7);
    dA[p] = (p * 256 + w * 64) * 8;
  }
  int rB[4], cB[4], dB[4];
#pragma unroll
  for (int p = 0; p < 4; ++p) {
    const int id = p * 256 + tid;
    rB[p] = id >> 3;
    cB[p] = (id & 7) ^ (rB[p] & 7);
    dB[p] = (p * 256 + w * 64) * 8;
  }

  f32x4 acc[4][8] = {};

  for (int k0 = 0; k0 < HIDN; k0 += 64) {
#pragma unroll
    for (int p = 0; p < 8; ++p)
      gload16(qbf + (size_t)(mt * 256 + rA[p]) * HIDN + k0 + cA[p] * 8,
              a_s + dA[p]);
#pragma unroll
    for (int p = 0; p < 4; ++p)
      gload16(wbf + (size_t)(nt * 128 + rB[p]) * HIDN + k0 + cB[p] * 8,
              b_s + dB[p]);
    __syncthreads();   // tiles resident
#pragma unroll
    for (int kk = 0; kk < 2; ++kk) {
      short8 af[4], bfv[8];
#pragma unroll
      for (int mi = 0; mi < 4; ++mi) {
        const int r = w * 64 + mi * 16 + lr;
        const int phys = (kk * 4 + lg) ^ (r & 7);
        af[mi] = *(const short8*)((const char*)a_s + r * 128 + phys * 16);
      }
#pragma unroll
      for (int ni = 0; ni < 8; ++ni) {
        const int r = ni * 16 + lr;
        const int phys = (kk * 4 + lg) ^ (r & 7);
        bfv[ni] = *(const short8*)((const char*)b_s + r * 128 + phys * 16);
      }
#pragma unroll
      for (int mi = 0; mi < 4; ++mi)
#pragma unroll
        for (int ni = 0; ni < 8; ++ni)
          acc[mi][ni] = MFMA(af[mi], bfv[ni], acc[mi][ni]);
    }
    __syncthreads();   // all reads done before restage
  }

#pragma unroll
  for (int mi = 0; mi < 4; ++mi)
#pragma unroll
    for (int ni = 0; ni < 8; ++ni)
#pragma unroll
      for (int r = 0; r < 4; ++r) {
        const int row = mt * 256 + w * 64 + mi * 16 + lg * 4 + r;  // [0,8192)
        const int colz = (nt & 7) * 128 + ni * 16 + lr;            // [0,1024)
        const float v = acc[mi][ni][r] + bias[colz];
        const int bi = row >> 11, s = row & (SQ - 1);
        const int h = colz >> 6, d = colz & (HD - 1);
        const int idx = ((bi * NH + h) * SQ + s) * HD + d;
        if (z == 0) {
          qh[idx] = f2bf(v * (0.125f * LOG2E) * mfl[row]);
        } else if (z == 1) {
          kh[idx] = f2bf(v * mfl[row]);
        } else {
          vh[idx] = f2bf(v);
        }
      }
}

// ---------------------------------------------------------------------------
// K2: per-column softmax denominators (exp2 domain). rcpL[j] = 1/sum_i 2^E2.
// ---------------------------------------------------------------------------
__global__ __launch_bounds__(256) void k_sumexp_m(
    const short* __restrict__ qh, const short* __restrict__ kh,
    float* __restrict__ rcpL)
{
  __shared__ short q_s[2][64][72];
  const int bh = blockIdx.y;
  const int jt = blockIdx.x;
  const int tid = threadIdx.x, w = tid >> 6, lane = tid & 63;
  const int lg = lane >> 4, lr = lane & 15;

  const int base = bh * SQ * HD;
  const int jbase = jt * 256 + w * 64;

  short8 bk[4][2];
#pragma unroll
  for (int jf = 0; jf < 4; ++jf) {
    const int j = jbase + jf * 16 + lr;
    bk[jf][0] = *(const short8*)(kh + base + j * HD + lg * 8);
    bk[jf][1] = *(const short8*)(kh + base + j * HD + 32 + lg * 8);
  }

  const int srow = tid >> 3, scc = (tid & 7) * 8;
  {
    const short8 s0 = *(const short8*)(qh + base + srow * HD + scc);
    const short8 s1 = *(const short8*)(qh + base + (32 + srow) * HD + scc);
    *(short8*)&q_s[0][srow][scc] = s0;
    *(short8*)&q_s[0][32 + srow][scc] = s1;
  }
  __syncthreads();

  f32x4 Lacc[4] = {};
  for (int t = 0; t < 32; ++t) {
    const int cur = t & 1;
    short8 n0, n1;
    if (t < 31) {
      const int ibn = (t + 1) * 64;
      n0 = *(const short8*)(qh + base + (ibn + srow) * HD + scc);
      n1 = *(const short8*)(qh + base + (ibn + 32 + srow) * HD + scc);
    }
#pragma unroll
    for (int s = 0; s < 4; ++s) {
      const short8 a0 = *(const short8*)&q_s[cur][s * 16 + lr][lg * 8];
      const short8 a1 = *(const short8*)&q_s[cur][s * 16 + lr][32 + lg * 8];
#pragma unroll
      for (int jf = 0; jf < 4; ++jf) {
        f32x4 e = {};
        e = MFMA(a0, bk[jf][0], e);
        e = MFMA(a1, bk[jf][1], e);
#pragma unroll
        for (int r = 0; r < 4; ++r)
          Lacc[jf][r] += exp2_raw(e[r]);
      }
    }
    if (t < 31) {
      __syncthreads();
      *(short8*)&q_s[cur ^ 1][srow][scc] = n0;
      *(short8*)&q_s[cur ^ 1][32 + srow][scc] = n1;
      __syncthreads();
    }
  }

#pragma unroll
  for (int jf = 0; jf < 4; ++jf) {
    float L = Lacc[jf][0] + Lacc[jf][1] + Lacc[jf][2] + Lacc[jf][3];
    L += __shfl_xor(L, 16, 64);
    L += __shfl_xor(L, 32, 64);
    if (lg == 0) rcpL[bh * SQ + jbase + jf * 16 + lr] = 1.0f / L;
  }
}

// ---------------------------------------------------------------------------
// K2b v2: transpose + scale V:  vT[bh][d][s] = vh[bh][s][d] * rcpL[bh][s].
// ---------------------------------------------------------------------------
__global__ __launch_bounds__(256) void k_vtrans(
    const short* __restrict__ vh, const float* __restrict__ rcpL,
    short* __restrict__ vT)
{
  __shared__ short t[64][72];
  const int bh = blockIdx.y;
  const int s0 = blockIdx.x * 64;
  const int tid = threadIdx.x;
  const int base = bh * SQ * HD;   // same for vh and vT
#pragma unroll
  for (int p = 0; p < 2; ++p) {
    const int id = p * 256 + tid;
    const int r = id >> 3, c = id & 7;
    const short8 v = *(const short8*)(vh + base + (s0 + r) * HD + c * 8);
    const float sc = rcpL[bh * SQ + s0 + r];
    float f[8];
#pragma unroll
    for (int e = 0; e < 8; ++e) {
      union { unsigned u; float x; } cv;
      cv.u = ((unsigned)(unsigned short)v[e]) << 16;
      f[e] = cv.x * sc;
    }
    union { unsigned u[4]; short8 s8; } o;
#pragma unroll
    for (int e = 0; e < 4; ++e) o.u[e] = cvtpk_bf16(f[2 * e], f[2 * e + 1]);
    *(short8*)&t[r][c * 8] = o.s8;
  }
  __syncthreads();
  const int d = tid >> 2, sc4 = (tid & 3) * 16;
  short val[16];
#pragma unroll
  for (int k = 0; k < 16; ++k) val[k] = t[sc4 + k][d];
  *(short8*)(vT + base + d * SQ + s0 + sc4) = *(const short8*)&val[0];
  *(short8*)(vT + base + d * SQ + s0 + sc4 + 8) = *(const short8*)&val[8];
}

// ---------------------------------------------------------------------------
// K3 v6: attention-weighted V (verified round 14, unchanged).
// ---------------------------------------------------------------------------
__global__ __launch_bounds__(256) void k_attnv(
    const short* __restrict__ qh, const short* __restrict__ kh,
    const short* __restrict__ vT,
    short* __restrict__ xo)
{
  __shared__ short k_s[64 * 64];
  __shared__ short v_s[64 * 64];
  __shared__ __attribute__((aligned(16))) short p_s[4][4][16][40];
  const int bh = blockIdx.y, b = bh >> 4, h = bh & (NH - 1);
  const int it = blockIdx.x;
  const int tid = threadIdx.x, w = tid >> 6, lane = tid & 63;
  const int lg = lane >> 4, lr = lane & 15;

  const int base = bh * SQ * HD;   // == bh*HD*SQ for vT
  const int i0 = it * 256 + w * 64;

  short8 aq[4][2];
#pragma unroll
  for (int fi = 0; fi < 4; ++fi) {
    aq[fi][0] = *(const short8*)(qh + base + (i0 + fi * 16 + lr) * HD + lg * 8);
    aq[fi][1] = *(const short8*)(qh + base + (i0 + fi * 16 + lr) * HD + 32 + lg * 8);
  }

  int strow[2], stphys[2], stbase[2];
#pragma unroll
  for (int p = 0; p < 2; ++p) {
    const int id = p * 256 + tid;
    const int r = id >> 3, c = id & 7;
    strow[p] = r;
    stphys[p] = c ^ (r & 7);
    stbase[p] = (p * 256 + w * 64) * 8;
  }

  f32x4 accx[4][4] = {};
  for (int jb = 0; jb < SQ; jb += 64) {
#pragma unroll
    for (int p = 0; p < 2; ++p) {
      gload16(kh + base + (size_t)(jb + strow[p]) * HD + stphys[p] * 8,
              k_s + stbase[p]);
      gload16(vT + base + (size_t)strow[p] * SQ + jb + stphys[p] * 8,
              v_s + stbase[p]);
    }
    __syncthreads();

#pragma unroll
    for (int sub = 0; sub < 2; ++sub) {
      short8 bk[2][2];
#pragma unroll
      for (int jj = 0; jj < 2; ++jj) {
        const int rr = sub * 32 + jj * 16 + lr;
        const int ph0 = lg ^ (rr & 7);
        const int ph1 = (4 + lg) ^ (rr & 7);
        bk[jj][0] = *(const short8*)(k_s + rr * 64 + ph0 * 8);
        bk[jj][1] = *(const short8*)(k_s + rr * 64 + ph1 * 8);
      }
      short8 bv[4];
#pragma unroll
      for (int nd = 0; nd < 4; ++nd) {
        const int rv = nd * 16 + lr;
        const int ph = (sub * 4 + lg) ^ (rv & 7);
        bv[nd] = *(const short8*)(v_s + rv * 64 + ph * 8);
      }

#pragma unroll
      for (int fi = 0; fi < 4; ++fi) {
        f32x4 e0 = {}, e1 = {};
        e0 = MFMA(bk[0][0], aq[fi][0], e0);
        e0 = MFMA(bk[0][1], aq[fi][1], e0);
        e1 = MFMA(bk[1][0], aq[fi][0], e1);
        e1 = MFMA(bk[1][1], aq[fi][1], e1);
        const unsigned u00 = cvtpk_bf16(exp2_raw(e0[0]), exp2_raw(e0[1]));
        const unsigned u01 = cvtpk_bf16(exp2_raw(e0[2]), exp2_raw(e0[3]));
        const unsigned u10 = cvtpk_bf16(exp2_raw(e1[0]), exp2_raw(e1[1]));
        const unsigned u11 = cvtpk_bf16(exp2_raw(e1[2]), exp2_raw(e1[3]));
        uint2 w0; w0.x = u00; w0.y = u01;
        uint2 w1; w1.x = u10; w1.y = u11;
        *(uint2*)&p_s[w][fi][lr][lg * 4] = w0;
        *(uint2*)&p_s[w][fi][lr][16 + lg * 4] = w1;
      }
#pragma unroll
      for (int fi = 0; fi < 4; ++fi) {
        const short8 pa = *(const short8*)&p_s[w][fi][lr][lg * 8];
#pragma unroll
        for (int nd = 0; nd < 4; ++nd)
          accx[fi][nd] = MFMA(pa, bv[nd], accx[fi][nd]);
      }
    }
    __syncthreads();
  }

#pragma unroll
  for (int fi = 0; fi < 4; ++fi)
#pragma unroll
    for (int nd = 0; nd < 4; ++nd)
#pragma unroll
      for (int r = 0; r < 4; ++r) {
        const int i = i0 + fi * 16 + lg * 4 + r, d = nd * 16 + lr;
        xo[(b * SQ + i) * HIDN + h * HD + d] = f2bf(accx[fi][nd][r]);
      }
}

// ---------------------------------------------------------------------------
// K4 v4: output projection, 2-phase 128^2 template + XCD swizzle. FP32 out.
// ---------------------------------------------------------------------------
__global__ __launch_bounds__(256) void k_proj_out2(
    const short* __restrict__ xb, const short* __restrict__ wo,
    const float* __restrict__ bo, float* __restrict__ out)
{
  __shared__ short a_s[2][128 * 64];
  __shared__ short b_s[2][128 * 64];
  // XCD swizzle: nwg = 8*64 = 512, chunk = 64 per XCD (bijective).
  const int flat = blockIdx.y * 8 + blockIdx.x;
  const int swz = (flat & 7) * 64 + (flat >> 3);
  const int nt = swz % 8, mt = swz / 8;
  const int tid = threadIdx.x;
  const int w = tid >> 6, lane = tid & 63;
  const int wr = w >> 1, wc = w & 1;
  const int lg = lane >> 4, lr = lane & 15;

  int srow[4], scs[4], sbase[4];
#pragma unroll
  for (int p = 0; p < 4; ++p) {
    const int id = p * 256 + tid;
    const int r = id >> 3, c = id & 7;
    srow[p] = r;
    scs[p] = c ^ (r & 7);
    sbase[p] = (p * 256 + w * 64) * 8;
  }

  f32x4 acc[4][4] = {};

#pragma unroll
  for (int p = 0; p < 4; ++p) {
    gload16(xb + (size_t)(mt * 128 + srow[p]) * HIDN + scs[p] * 8, a_s[0] + sbase[p]);
    gload16(wo + (size_t)(nt * 128 + srow[p]) * HIDN + scs[p] * 8, b_s[0] + sbase[p]);
  }
  __syncthreads();

  int cur = 0;
  for (int k0 = 0; k0 < HIDN; k0 += 64) {
    if (k0 + 64 < HIDN) {
      const int kn = k0 + 64;
#pragma unroll
      for (int p = 0; p < 4; ++p) {
        gload16(xb + (size_t)(mt * 128 + srow[p]) * HIDN + kn + scs[p] * 8,
                a_s[cur ^ 1] + sbase[p]);
        gload16(wo + (size_t)(nt * 128 + srow[p]) * HIDN + kn + scs[p] * 8,
                b_s[cur ^ 1] + sbase[p]);
      }
    }
#pragma unroll
    for (int kk = 0; kk < 2; ++kk) {
      short8 af[4], bfv[4];
#pragma unroll
      for (int mi = 0; mi < 4; ++mi) {
        const int r = wr * 64 + mi * 16 + lr;
        const int phys = (kk * 4 + lg) ^ (r & 7);
        af[mi] = *(const short8*)((const char*)a_s[cur] + r * 128 + phys * 16);
      }
#pragma unroll
      for (int ni = 0; ni < 4; ++ni) {
        const int r = wc * 64 + ni * 16 + lr;
        const int phys = (kk * 4 + lg) ^ (r & 7);
        bfv[ni] = *(const short8*)((const char*)b_s[cur] + r * 128 + phys * 16);
      }
#pragma unroll
      for (int mi = 0; mi < 4; ++mi)
#pragma unroll
        for (int ni = 0; ni < 4; ++ni)
          acc[mi][ni] = MFMA(af[mi], bfv[ni], acc[mi][ni]);
    }
    __syncthreads();
    cur ^= 1;
  }

#pragma unroll
  for (int mi = 0; mi < 4; ++mi)
#pragma unroll
    for (int ni = 0; ni < 4; ++ni)
#pragma unroll
      for (int r = 0; r < 4; ++r) {
        const int row = mt * 128 + wr * 64 + mi * 16 + lg * 4 + r;
        const int col = nt * 128 + wc * 64 + ni * 16 + lr;
        out[row * HIDN + col] = acc[mi][ni][r] + bo[col];
      }
}

// ---------------------------------------------------------------------------
extern "C" void kernel_launch(void* const* d_in, const int* in_sizes, int n_in,
                              void* d_out, int out_size, void* d_ws, size_t ws_size,
                              hipStream_t stream) {
  const float* query = (const float*)d_in[0];
  const unsigned* mraw = (const unsigned*)d_in[1];
  const float* Wq = (const float*)d_in[2];
  const float* bq = (const float*)d_in[3];
  const float* Wk = (const float*)d_in[4];
  const float* bk = (const float*)d_in[5];
  const float* Wv = (const float*)d_in[6];
  const float* bv = (const float*)d_in[7];
  const float* Wo = (const float*)d_in[8];
  const float* bo = (const float*)d_in[9];

  // ws (shorts): qh 16.78M | kh 16.78M | vT 16.78M | xb 16.78M | rcpL 0.52M | mfl 32K
  short* qh  = (short*)d_ws;
  short* kh  = qh + (NB * NH * SQ * HD);
  short* vT  = kh + (NB * NH * SQ * HD);
  short* xb  = vT + (NB * NH * SQ * HD);
  float* rcpL = (float*)(xb + (NB * SQ * HIDN));
  float* mfl = rcpL + (NB * NH * SQ);

  // vh (row-major V) parks in the xb region: consumed by k_vtrans before
  // k_attnv overwrites xb with its output.
  short* vh = xb;

  // bf16 staging scratch parked in d_out (dead before k_proj_out2 writes it)
  short* qbf = (short*)d_out;
  short* wbf = qbf + (NB * SQ * HIDN);
  // Wo-bf16 lives in the qh region (dead after k_attnv)
  short* wo  = qh;

  k_maskprep<<<dim3(1), dim3(256), 0, stream>>>(mraw, mfl);
  k_cvt<<<dim3((NB * SQ * HIDN) / 1024, 4), dim3(256), 0, stream>>>(
      query, Wq, Wk, Wv, qbf, wbf);
  k_proj_qkv4<<<dim3(24, 32), dim3(256), 0, stream>>>(
      qbf, wbf, bq, bk, bv, mfl, qh, kh, vh);
  k_sumexp_m<<<dim3(SQ / 256, NB * NH), dim3(256), 0, stream>>>(qh, kh, rcpL);
  k_vtrans<<<dim3(SQ / 64, NB * NH), dim3(256), 0, stream>>>(vh, rcpL, vT);
  k_attnv<<<dim3(SQ / 256, NB * NH), dim3(256), 0, stream>>>(qh, kh, vT, xb);
  k_cvtWo<<<dim3((HIDN * HIDN) / 1024), dim3(256), 0, stream>>>(Wo, wo);
  k_proj_out2<<<dim3(HIDN / 128, (NB * SQ) / 128), dim3(256), 0, stream>>>(
      xb, wo, bo, (float*)d_out);
}

// Round 20
// 273.954 us; speedup vs baseline: 1.1818x; 1.1818x over previous
//
#include <hip/hip_runtime.h>

#define SQ   2048
#define HIDN 1024
#define NB   4
#define NH   16
#define HD   64

typedef __attribute__((ext_vector_type(8))) short short8;
typedef __attribute__((ext_vector_type(4))) short short4v;
typedef __attribute__((ext_vector_type(4))) float f32x4;

__device__ __forceinline__ short f2bf(float f) {
  union { float f; unsigned u; } x; x.f = f;
  unsigned r = (x.u + 0x7fffu + ((x.u >> 16) & 1u)) >> 16;
  return (short)r;
}

__device__ __forceinline__ unsigned cvtpk_bf16(float lo, float hi) {
  unsigned u;
  asm("v_cvt_pk_bf16_f32 %0, %1, %2" : "=v"(u) : "v"(lo), "v"(hi));
  return u;
}

__device__ __forceinline__ float exp2_raw(float x) {
  float r;
  asm("v_exp_f32 %0, %1" : "=v"(r) : "v"(x));   // r = 2^x, register-only
  return r;
}

#define MFMA(a, b, c) __builtin_amdgcn_mfma_f32_16x16x32_bf16((a), (b), (c), 0, 0, 0)

__device__ __forceinline__ void gload16(const void* g, void* l) {
  __builtin_amdgcn_global_load_lds(
      (const __attribute__((address_space(1))) unsigned*)g,
      (__attribute__((address_space(3))) unsigned*)l, 16, 0, 0);
}

#define LOG2E 1.44269504f

// ---------------------------------------------------------------------------
// K0: normalize mask to fp32 (auto-detect int32 / byte-bool / fp32). Verified.
// ---------------------------------------------------------------------------
__global__ __launch_bounds__(256) void k_maskprep(const unsigned* __restrict__ mraw,
                                                  float* __restrict__ m) {
  __shared__ unsigned red[256];
  const int tid = threadIdx.x;
  unsigned w_or = 0;
  for (int i = tid; i < 2048; i += 256) w_or |= mraw[i];
  red[tid] = w_or;
  __syncthreads();
  for (int s = 128; s > 0; s >>= 1) {
    if (tid < s) red[tid] |= red[tid + s];
    __syncthreads();
  }
  const unsigned allw = red[0];
  int mode;
  if ((allw & 0xFFFFFFFEu) == 0) mode = 0;
  else if ((allw & 0xFEFEFEFEu) == 0) mode = 1;
  else mode = 2;
  const unsigned char* mb = (const unsigned char*)mraw;
  const float* mf = (const float*)mraw;
  const int* mi = (const int*)mraw;
  for (int i = tid; i < NB * SQ; i += 256) {
    float v;
    if (mode == 0)      v = mi[i] ? 1.0f : 0.0f;
    else if (mode == 1) v = mb[i] ? 1.0f : 0.0f;
    else                v = (mf[i] != 0.0f) ? 1.0f : 0.0f;
    m[i] = v;
  }
}

// ---------------------------------------------------------------------------
// K0b: fp32 -> bf16 pre-convert. y=0: query -> qbf; y=1..3: Wq/Wk/Wv -> wbf.
// ---------------------------------------------------------------------------
__global__ __launch_bounds__(256) void k_cvt(
    const float* __restrict__ query, const float* __restrict__ Wq,
    const float* __restrict__ Wk, const float* __restrict__ Wv,
    short* __restrict__ qbf, short* __restrict__ wbf)
{
  const int yy = blockIdx.y;
  const float* __restrict__ src = (yy == 0) ? query : (yy == 1) ? Wq : (yy == 2) ? Wk : Wv;
  short* __restrict__ dst = (yy == 0) ? qbf : wbf + (yy - 1) * (HIDN * HIDN);
  const int n = (yy == 0) ? (NB * SQ * HIDN) : (HIDN * HIDN);
  const int i = (blockIdx.x * 256 + threadIdx.x) * 4;
  if (i >= n) return;
  const f32x4 v = *(const f32x4*)(src + i);
  short4v s;
#pragma unroll
  for (int e = 0; e < 4; ++e) s[e] = f2bf(v[e]);
  *(short4v*)(dst + i) = s;
}

// K0c: Wo -> bf16 (runs after attnv, into the then-dead qh region).
__global__ __launch_bounds__(256) void k_cvtWo(
    const float* __restrict__ Wo, short* __restrict__ wo)
{
  const int i = (blockIdx.x * 256 + threadIdx.x) * 4;
  if (i >= HIDN * HIDN) return;
  const f32x4 v = *(const f32x4*)(Wo + i);
  short4v s;
#pragma unroll
  for (int e = 0; e < 4; ++e) s[e] = f2bf(v[e]);
  *(short4v*)(wo + i) = s;
}

// ---------------------------------------------------------------------------
// K1 (round-16 verified best): fused QKV projection GEMM, 2-phase
// double-buffered 128^2, BK=64, gload_lds + both-sides XOR swizzle.
// qh scale 0.125*log2(e); mask folded into q,k; z=2 writes vh row-major.
// ---------------------------------------------------------------------------
__global__ __launch_bounds__(256) void k_proj_qkv2(
    const short* __restrict__ qbf, const short* __restrict__ wbf,
    const float* __restrict__ bq, const float* __restrict__ bkb,
    const float* __restrict__ bv, const float* __restrict__ mfl,
    short* __restrict__ qh, short* __restrict__ kh, short* __restrict__ vh)
{
  __shared__ short a_s[2][128 * 64];
  __shared__ short b_s[2][128 * 64];
  const int nt = blockIdx.x, mt = blockIdx.y;
  const int tid = threadIdx.x;
  const int w = tid >> 6, lane = tid & 63;
  const int wr = w >> 1, wc = w & 1;
  const int lg = lane >> 4, lr = lane & 15;

  const int z = nt >> 3;   // block-uniform
  const float* __restrict__ bias = (z == 0) ? bq : (z == 1) ? bkb : bv;

  int srow[4], scs[4], sbase[4];
#pragma unroll
  for (int p = 0; p < 4; ++p) {
    const int id = p * 256 + tid;
    const int r = id >> 3, c = id & 7;
    srow[p] = r;
    scs[p] = c ^ (r & 7);
    sbase[p] = (p * 256 + w * 64) * 8;
  }

  f32x4 acc[4][4] = {};

  // prologue: stage tile 0
#pragma unroll
  for (int p = 0; p < 4; ++p) {
    gload16(qbf + (size_t)(mt * 128 + srow[p]) * HIDN + scs[p] * 8, a_s[0] + sbase[p]);
    gload16(wbf + (size_t)(nt * 128 + srow[p]) * HIDN + scs[p] * 8, b_s[0] + sbase[p]);
  }
  __syncthreads();

  int cur = 0;
  for (int k0 = 0; k0 < HIDN; k0 += 64) {
    if (k0 + 64 < HIDN) {   // issue next tile's loads BEFORE compute
      const int kn = k0 + 64;
#pragma unroll
      for (int p = 0; p < 4; ++p) {
        gload16(qbf + (size_t)(mt * 128 + srow[p]) * HIDN + kn + scs[p] * 8,
                a_s[cur ^ 1] + sbase[p]);
        gload16(wbf + (size_t)(nt * 128 + srow[p]) * HIDN + kn + scs[p] * 8,
                b_s[cur ^ 1] + sbase[p]);
      }
    }
#pragma unroll
    for (int kk = 0; kk < 2; ++kk) {
      short8 af[4], bfv[4];
#pragma unroll
      for (int mi = 0; mi < 4; ++mi) {
        const int r = wr * 64 + mi * 16 + lr;
        const int phys = (kk * 4 + lg) ^ (r & 7);
        af[mi] = *(const short8*)((const char*)a_s[cur] + r * 128 + phys * 16);
      }
#pragma unroll
      for (int ni = 0; ni < 4; ++ni) {
        const int r = wc * 64 + ni * 16 + lr;
        const int phys = (kk * 4 + lg) ^ (r & 7);
        bfv[ni] = *(const short8*)((const char*)b_s[cur] + r * 128 + phys * 16);
      }
#pragma unroll
      for (int mi = 0; mi < 4; ++mi)
#pragma unroll
        for (int ni = 0; ni < 4; ++ni)
          acc[mi][ni] = MFMA(af[mi], bfv[ni], acc[mi][ni]);
    }
    __syncthreads();   // drains vmcnt (next-tile stages) + lgkm (our ds_reads)
    cur ^= 1;
  }

#pragma unroll
  for (int mi = 0; mi < 4; ++mi)
#pragma unroll
    for (int ni = 0; ni < 4; ++ni)
#pragma unroll
      for (int r = 0; r < 4; ++r) {
        const int row = mt * 128 + wr * 64 + mi * 16 + lg * 4 + r;  // [0,8192)
        const int colz = (nt & 7) * 128 + wc * 64 + ni * 16 + lr;   // [0,1024)
        const float v = acc[mi][ni][r] + bias[colz];
        const int bi = row >> 11, s = row & (SQ - 1);
        const int h = colz >> 6, d = colz & (HD - 1);
        const int idx = ((bi * NH + h) * SQ + s) * HD + d;
        if (z == 0) {
          qh[idx] = f2bf(v * (0.125f * LOG2E) * mfl[row]);
        } else if (z == 1) {
          kh[idx] = f2bf(v * mfl[row]);
        } else {
          vh[idx] = f2bf(v);
        }
      }
}

// ---------------------------------------------------------------------------
// K2 v4: per-column softmax denominators (exp2 domain) FUSED with the V
// transpose+scale: after computing 1/L for its 256 columns (kept in LDS,
// no global round-trip), the block scales/transposes the same 256 V rows:
// vT[bh][d][j] = vh[bh][j][d] / L[j].  Arithmetic identical to the old
// vtrans path, so absmax is unchanged.
// ---------------------------------------------------------------------------
__global__ __launch_bounds__(256) void k_sumexp_m(
    const short* __restrict__ qh, const short* __restrict__ kh,
    const short* __restrict__ vh, short* __restrict__ vT)
{
  __shared__ short q_s[2][64][72];
  __shared__ float rl_s[256];
  __shared__ short t_s[64][72];
  const int bh = blockIdx.y;
  const int jt = blockIdx.x;
  const int tid = threadIdx.x, w = tid >> 6, lane = tid & 63;
  const int lg = lane >> 4, lr = lane & 15;

  const int base = bh * SQ * HD;
  const int jbase = jt * 256 + w * 64;

  short8 bk[4][2];
#pragma unroll
  for (int jf = 0; jf < 4; ++jf) {
    const int j = jbase + jf * 16 + lr;
    bk[jf][0] = *(const short8*)(kh + base + j * HD + lg * 8);
    bk[jf][1] = *(const short8*)(kh + base + j * HD + 32 + lg * 8);
  }

  const int srow = tid >> 3, scc = (tid & 7) * 8;
  {
    const short8 s0 = *(const short8*)(qh + base + srow * HD + scc);
    const short8 s1 = *(const short8*)(qh + base + (32 + srow) * HD + scc);
    *(short8*)&q_s[0][srow][scc] = s0;
    *(short8*)&q_s[0][32 + srow][scc] = s1;
  }
  __syncthreads();

  f32x4 Lacc[4] = {};
  for (int t = 0; t < 32; ++t) {
    const int cur = t & 1;
    short8 n0, n1;
    if (t < 31) {
      const int ibn = (t + 1) * 64;
      n0 = *(const short8*)(qh + base + (ibn + srow) * HD + scc);
      n1 = *(const short8*)(qh + base + (ibn + 32 + srow) * HD + scc);
    }
#pragma unroll
    for (int s = 0; s < 4; ++s) {
      const short8 a0 = *(const short8*)&q_s[cur][s * 16 + lr][lg * 8];
      const short8 a1 = *(const short8*)&q_s[cur][s * 16 + lr][32 + lg * 8];
#pragma unroll
      for (int jf = 0; jf < 4; ++jf) {
        f32x4 e = {};
        e = MFMA(a0, bk[jf][0], e);
        e = MFMA(a1, bk[jf][1], e);
#pragma unroll
        for (int r = 0; r < 4; ++r)
          Lacc[jf][r] += exp2_raw(e[r]);
      }
    }
    if (t < 31) {
      __syncthreads();
      *(short8*)&q_s[cur ^ 1][srow][scc] = n0;
      *(short8*)&q_s[cur ^ 1][32 + srow][scc] = n1;
      __syncthreads();
    }
  }

#pragma unroll
  for (int jf = 0; jf < 4; ++jf) {
    float L = Lacc[jf][0] + Lacc[jf][1] + Lacc[jf][2] + Lacc[jf][3];
    L += __shfl_xor(L, 16, 64);
    L += __shfl_xor(L, 32, 64);
    if (lg == 0) rl_s[w * 64 + jf * 16 + lr] = 1.0f / L;
  }
  __syncthreads();   // rl_s complete for all 256 columns

  // fused V transpose+scale for this block's 256 j-rows (4 sub-tiles of 64)
  const int jglob0 = jt * 256;
  for (int sub = 0; sub < 4; ++sub) {
#pragma unroll
    for (int p = 0; p < 2; ++p) {
      const int id = p * 256 + tid;
      const int r = id >> 3, c = id & 7;
      const short8 v = *(const short8*)(vh + base + (jglob0 + sub * 64 + r) * HD + c * 8);
      const float sc = rl_s[sub * 64 + r];
      float f[8];
#pragma unroll
      for (int e = 0; e < 8; ++e) {
        union { unsigned u; float x; } cv;
        cv.u = ((unsigned)(unsigned short)v[e]) << 16;
        f[e] = cv.x * sc;
      }
      union { unsigned u[4]; short8 s8; } o;
#pragma unroll
      for (int e = 0; e < 4; ++e) o.u[e] = cvtpk_bf16(f[2 * e], f[2 * e + 1]);
      *(short8*)&t_s[r][c * 8] = o.s8;
    }
    __syncthreads();
    const int d = tid >> 2, sc4 = (tid & 3) * 16;
    short val[16];
#pragma unroll
    for (int k = 0; k < 16; ++k) val[k] = t_s[sc4 + k][d];
    *(short8*)(vT + base + d * SQ + jglob0 + sub * 64 + sc4) = *(const short8*)&val[0];
    *(short8*)(vT + base + d * SQ + jglob0 + sub * 64 + sc4 + 8) = *(const short8*)&val[8];
    __syncthreads();   // t_s reads done before next sub overwrites
  }
}

// ---------------------------------------------------------------------------
// K3 v6: attention-weighted V (verified round 14, unchanged).
// ---------------------------------------------------------------------------
__global__ __launch_bounds__(256) void k_attnv(
    const short* __restrict__ qh, const short* __restrict__ kh,
    const short* __restrict__ vT,
    short* __restrict__ xo)
{
  __shared__ short k_s[64 * 64];
  __shared__ short v_s[64 * 64];
  __shared__ __attribute__((aligned(16))) short p_s[4][4][16][40];
  const int bh = blockIdx.y, b = bh >> 4, h = bh & (NH - 1);
  const int it = blockIdx.x;
  const int tid = threadIdx.x, w = tid >> 6, lane = tid & 63;
  const int lg = lane >> 4, lr = lane & 15;

  const int base = bh * SQ * HD;   // == bh*HD*SQ for vT
  const int i0 = it * 256 + w * 64;

  short8 aq[4][2];
#pragma unroll
  for (int fi = 0; fi < 4; ++fi) {
    aq[fi][0] = *(const short8*)(qh + base + (i0 + fi * 16 + lr) * HD + lg * 8);
    aq[fi][1] = *(const short8*)(qh + base + (i0 + fi * 16 + lr) * HD + 32 + lg * 8);
  }

  int strow[2], stphys[2], stbase[2];
#pragma unroll
  for (int p = 0; p < 2; ++p) {
    const int id = p * 256 + tid;
    const int r = id >> 3, c = id & 7;
    strow[p] = r;
    stphys[p] = c ^ (r & 7);
    stbase[p] = (p * 256 + w * 64) * 8;
  }

  f32x4 accx[4][4] = {};
  for (int jb = 0; jb < SQ; jb += 64) {
#pragma unroll
    for (int p = 0; p < 2; ++p) {
      gload16(kh + base + (size_t)(jb + strow[p]) * HD + stphys[p] * 8,
              k_s + stbase[p]);
      gload16(vT + base + (size_t)strow[p] * SQ + jb + stphys[p] * 8,
              v_s + stbase[p]);
    }
    __syncthreads();

#pragma unroll
    for (int sub = 0; sub < 2; ++sub) {
      short8 bk[2][2];
#pragma unroll
      for (int jj = 0; jj < 2; ++jj) {
        const int rr = sub * 32 + jj * 16 + lr;
        const int ph0 = lg ^ (rr & 7);
        const int ph1 = (4 + lg) ^ (rr & 7);
        bk[jj][0] = *(const short8*)(k_s + rr * 64 + ph0 * 8);
        bk[jj][1] = *(const short8*)(k_s + rr * 64 + ph1 * 8);
      }
      short8 bv[4];
#pragma unroll
      for (int nd = 0; nd < 4; ++nd) {
        const int rv = nd * 16 + lr;
        const int ph = (sub * 4 + lg) ^ (rv & 7);
        bv[nd] = *(const short8*)(v_s + rv * 64 + ph * 8);
      }

#pragma unroll
      for (int fi = 0; fi < 4; ++fi) {
        f32x4 e0 = {}, e1 = {};
        e0 = MFMA(bk[0][0], aq[fi][0], e0);
        e0 = MFMA(bk[0][1], aq[fi][1], e0);
        e1 = MFMA(bk[1][0], aq[fi][0], e1);
        e1 = MFMA(bk[1][1], aq[fi][1], e1);
        const unsigned u00 = cvtpk_bf16(exp2_raw(e0[0]), exp2_raw(e0[1]));
        const unsigned u01 = cvtpk_bf16(exp2_raw(e0[2]), exp2_raw(e0[3]));
        const unsigned u10 = cvtpk_bf16(exp2_raw(e1[0]), exp2_raw(e1[1]));
        const unsigned u11 = cvtpk_bf16(exp2_raw(e1[2]), exp2_raw(e1[3]));
        uint2 w0; w0.x = u00; w0.y = u01;
        uint2 w1; w1.x = u10; w1.y = u11;
        *(uint2*)&p_s[w][fi][lr][lg * 4] = w0;
        *(uint2*)&p_s[w][fi][lr][16 + lg * 4] = w1;
      }
#pragma unroll
      for (int fi = 0; fi < 4; ++fi) {
        const short8 pa = *(const short8*)&p_s[w][fi][lr][lg * 8];
#pragma unroll
        for (int nd = 0; nd < 4; ++nd)
          accx[fi][nd] = MFMA(pa, bv[nd], accx[fi][nd]);
      }
    }
    __syncthreads();
  }

#pragma unroll
  for (int fi = 0; fi < 4; ++fi)
#pragma unroll
    for (int nd = 0; nd < 4; ++nd)
#pragma unroll
      for (int r = 0; r < 4; ++r) {
        const int i = i0 + fi * 16 + lg * 4 + r, d = nd * 16 + lr;
        xo[(b * SQ + i) * HIDN + h * HD + d] = f2bf(accx[fi][nd][r]);
      }
}

// ---------------------------------------------------------------------------
// K4 v4: output projection, 2-phase 128^2 template + XCD swizzle. FP32 out.
// ---------------------------------------------------------------------------
__global__ __launch_bounds__(256) void k_proj_out2(
    const short* __restrict__ xb, const short* __restrict__ wo,
    const float* __restrict__ bo, float* __restrict__ out)
{
  __shared__ short a_s[2][128 * 64];
  __shared__ short b_s[2][128 * 64];
  // XCD swizzle: nwg = 8*64 = 512, chunk = 64 per XCD (bijective).
  const int flat = blockIdx.y * 8 + blockIdx.x;
  const int swz = (flat & 7) * 64 + (flat >> 3);
  const int nt = swz % 8, mt = swz / 8;
  const int tid = threadIdx.x;
  const int w = tid >> 6, lane = tid & 63;
  const int wr = w >> 1, wc = w & 1;
  const int lg = lane >> 4, lr = lane & 15;

  int srow[4], scs[4], sbase[4];
#pragma unroll
  for (int p = 0; p < 4; ++p) {
    const int id = p * 256 + tid;
    const int r = id >> 3, c = id & 7;
    srow[p] = r;
    scs[p] = c ^ (r & 7);
    sbase[p] = (p * 256 + w * 64) * 8;
  }

  f32x4 acc[4][4] = {};

#pragma unroll
  for (int p = 0; p < 4; ++p) {
    gload16(xb + (size_t)(mt * 128 + srow[p]) * HIDN + scs[p] * 8, a_s[0] + sbase[p]);
    gload16(wo + (size_t)(nt * 128 + srow[p]) * HIDN + scs[p] * 8, b_s[0] + sbase[p]);
  }
  __syncthreads();

  int cur = 0;
  for (int k0 = 0; k0 < HIDN; k0 += 64) {
    if (k0 + 64 < HIDN) {
      const int kn = k0 + 64;
#pragma unroll
      for (int p = 0; p < 4; ++p) {
        gload16(xb + (size_t)(mt * 128 + srow[p]) * HIDN + kn + scs[p] * 8,
                a_s[cur ^ 1] + sbase[p]);
        gload16(wo + (size_t)(nt * 128 + srow[p]) * HIDN + kn + scs[p] * 8,
                b_s[cur ^ 1] + sbase[p]);
      }
    }
#pragma unroll
    for (int kk = 0; kk < 2; ++kk) {
      short8 af[4], bfv[4];
#pragma unroll
      for (int mi = 0; mi < 4; ++mi) {
        const int r = wr * 64 + mi * 16 + lr;
        const int phys = (kk * 4 + lg) ^ (r & 7);
        af[mi] = *(const short8*)((const char*)a_s[cur] + r * 128 + phys * 16);
      }
#pragma unroll
      for (int ni = 0; ni < 4; ++ni) {
        const int r = wc * 64 + ni * 16 + lr;
        const int phys = (kk * 4 + lg) ^ (r & 7);
        bfv[ni] = *(const short8*)((const char*)b_s[cur] + r * 128 + phys * 16);
      }
#pragma unroll
      for (int mi = 0; mi < 4; ++mi)
#pragma unroll
        for (int ni = 0; ni < 4; ++ni)
          acc[mi][ni] = MFMA(af[mi], bfv[ni], acc[mi][ni]);
    }
    __syncthreads();
    cur ^= 1;
  }

#pragma unroll
  for (int mi = 0; mi < 4; ++mi)
#pragma unroll
    for (int ni = 0; ni < 4; ++ni)
#pragma unroll
      for (int r = 0; r < 4; ++r) {
        const int row = mt * 128 + wr * 64 + mi * 16 + lg * 4 + r;
        const int col = nt * 128 + wc * 64 + ni * 16 + lr;
        out[row * HIDN + col] = acc[mi][ni][r] + bo[col];
      }
}

// ---------------------------------------------------------------------------
extern "C" void kernel_launch(void* const* d_in, const int* in_sizes, int n_in,
                              void* d_out, int out_size, void* d_ws, size_t ws_size,
                              hipStream_t stream) {
  const float* query = (const float*)d_in[0];
  const unsigned* mraw = (const unsigned*)d_in[1];
  const float* Wq = (const float*)d_in[2];
  const float* bq = (const float*)d_in[3];
  const float* Wk = (const float*)d_in[4];
  const float* bk = (const float*)d_in[5];
  const float* Wv = (const float*)d_in[6];
  const float* bv = (const float*)d_in[7];
  const float* Wo = (const float*)d_in[8];
  const float* bo = (const float*)d_in[9];

  // ws (shorts): qh 16.78M | kh 16.78M | vT 16.78M | xb 16.78M | mfl 32K
  short* qh  = (short*)d_ws;
  short* kh  = qh + (NB * NH * SQ * HD);
  short* vT  = kh + (NB * NH * SQ * HD);
  short* xb  = vT + (NB * NH * SQ * HD);
  float* mfl = (float*)(xb + (NB * SQ * HIDN));

  // vh (row-major V) parks in the xb region: consumed by fused sumexp before
  // k_attnv overwrites xb with its output.
  short* vh = xb;

  // bf16 staging scratch parked in d_out (dead before k_proj_out2 writes it)
  short* qbf = (short*)d_out;
  short* wbf = qbf + (NB * SQ * HIDN);
  // Wo-bf16 lives in the qh region (dead after k_attnv)
  short* wo  = qh;

  k_maskprep<<<dim3(1), dim3(256), 0, stream>>>(mraw, mfl);
  k_cvt<<<dim3((NB * SQ * HIDN) / 1024, 4), dim3(256), 0, stream>>>(
      query, Wq, Wk, Wv, qbf, wbf);
  k_proj_qkv2<<<dim3(24, 64), dim3(256), 0, stream>>>(
      qbf, wbf, bq, bk, bv, mfl, qh, kh, vh);
  k_sumexp_m<<<dim3(SQ / 256, NB * NH), dim3(256), 0, stream>>>(qh, kh, vh, vT);
  k_attnv<<<dim3(SQ / 256, NB * NH), dim3(256), 0, stream>>>(qh, kh, vT, xb);
  k_cvtWo<<<dim3((HIDN * HIDN) / 1024), dim3(256), 0, stream>>>(Wo, wo);
  k_proj_out2<<<dim3(HIDN / 128, (NB * SQ) / 128), dim3(256), 0, stream>>>(
      xb, wo, bo, (float*)d_out);
}